// Round 8
// baseline (664.396 us; speedup 1.0000x reference)
//
#include <hip/hip_runtime.h>

#define M_NODES 100000
#define DIM 128
#define N_EDGES_TOT 1600000
#define NBKT 256
#define NPB 391      // nodes per bucket; 256*391 = 100096 >= 100000
#define BKT_CAP 8192 // LDS staging capacity (mean bucket = 6250 edges)

typedef unsigned int uint;
typedef unsigned short ushort;
typedef __attribute__((ext_vector_type(8))) short bf16x8;
typedef __attribute__((ext_vector_type(4))) float f32x4;

__device__ __forceinline__ float bflo(uint u) { return __uint_as_float(u << 16); }
__device__ __forceinline__ float bfhi(uint u) { return __uint_as_float(u & 0xffff0000u); }
__device__ __forceinline__ float bf2f(ushort h) { return __uint_as_float(((uint)h) << 16); }
__device__ __forceinline__ ushort f2bf(float f) {
    uint u = __float_as_uint(f);
    return (ushort)((u + 0x7fffu + ((u >> 16) & 1u)) >> 16);
}

// ---------------------------------------------------------------------------
__global__ void k_zerof(float* p, int n) {
    int i = blockIdx.x * 256 + threadIdx.x;
    if (i < n) p[i] = 0.f;
}

// ---------------------------------------------------------------------------
// x f32 -> bf16
__global__ void k_cvt(const float* __restrict__ x, ushort* __restrict__ xb,
                      int n4) {
    int i = blockIdx.x * 256 + threadIdx.x;
    if (i >= n4) return;
    float4 v = ((const float4*)x)[i];
    uint2 r;
    r.x = (uint)f2bf(v.x) | ((uint)f2bf(v.y) << 16);
    r.y = (uint)f2bf(v.z) | ((uint)f2bf(v.w) << 16);
    ((uint2*)xb)[i] = r;
}

// W (K x N f32) -> transposed split planes Wh/Wl (N x K bf16), 6 matrices.
__global__ void k_wprep(const float* __restrict__ W1,
                        const float* __restrict__ W2, ushort* __restrict__ Wh,
                        ushort* __restrict__ Wl) {
    int i = blockIdx.x * 256 + threadIdx.x;
    if (i >= 6 * 16384) return;
    int l = i >> 14;
    int r = i & 16383;
    int n = r >> 7, k = r & 127;
    const float* W = (l < 3) ? (W1 + l * 16384) : (W2 + (l - 3) * 16384);
    float w = W[k * 128 + n];
    ushort h = f2bf(w);
    Wh[i] = h;
    Wl[i] = f2bf(w - bf2f(h));
}

// ---------------------------------------------------------------------------
// CSR build, bucket-radix, no global atomics.
__global__ void k_bhist(const int* __restrict__ dst, int* __restrict__ cntM,
                        int nE, int nChunks) {
    __shared__ int h[NBKT];
    const int chunk = blockIdx.x, t = threadIdx.x;
    h[t] = 0;
    __syncthreads();
    const int e0 = chunk * 2048;
#pragma unroll
    for (int k = 0; k < 8; ++k) {
        int e = e0 + k * 256 + t;
        if (e < nE) atomicAdd(&h[dst[e] / NPB], 1);
    }
    __syncthreads();
    cntM[t * nChunks + chunk] = h[t];
}

__global__ void k_scanA(int* __restrict__ cnt, int* __restrict__ bsum, int n) {
    __shared__ int s[256];
    int t = threadIdx.x, i = blockIdx.x * 256 + t;
    int v = (i < n) ? cnt[i] : 0;
    s[t] = v;
    __syncthreads();
#pragma unroll
    for (int o = 1; o < 256; o <<= 1) {
        int a = (t >= o) ? s[t - o] : 0;
        __syncthreads();
        s[t] += a;
        __syncthreads();
    }
    if (i < n) cnt[i] = s[t] - v;
    if (t == 255) bsum[blockIdx.x] = s[255];
}

__global__ void k_scanB(int* bsum, int nB) {
    __shared__ int s[1024];
    int t = threadIdx.x;
    int v = (t < nB) ? bsum[t] : 0;
    s[t] = v;
    __syncthreads();
#pragma unroll
    for (int o = 1; o < 1024; o <<= 1) {
        int a = (t >= o) ? s[t - o] : 0;
        __syncthreads();
        s[t] += a;
        __syncthreads();
    }
    if (t < nB) bsum[t] = s[t] - v;
}

__global__ void k_scanC(int* __restrict__ excl, const int* __restrict__ bsum) {
    int i = blockIdx.x * 256 + threadIdx.x;
    excl[i] += bsum[blockIdx.x];
}

__global__ void k_pairs(const int* __restrict__ src, const int* __restrict__ dst,
                        const int* __restrict__ exclM, int2* __restrict__ pairs,
                        int nE, int nChunks) {
    __shared__ int base[NBKT];
    const int chunk = blockIdx.x, t = threadIdx.x;
    base[t] = exclM[t * nChunks + chunk];
    __syncthreads();
    const int e0 = chunk * 2048;
#pragma unroll
    for (int k = 0; k < 8; ++k) {
        int e = e0 + k * 256 + t;
        if (e < nE) {
            int d = dst[e];
            int pos = atomicAdd(&base[d / NPB], 1);
            pairs[pos] = make_int2(d, src[e]);
        }
    }
}

__global__ void k_csrD(const int2* __restrict__ pairs,
                       const int* __restrict__ exclM, int nChunks,
                       int* __restrict__ rowptr, int* __restrict__ srcs,
                       int nE) {
    __shared__ int cnt[512];
    __shared__ int scn[512];
    __shared__ int sl[BKT_CAP];
    const int b = blockIdx.x, t = threadIdx.x;
    const int base = exclM[b * nChunks];
    const int next = (b == NBKT - 1) ? nE : exclM[(b + 1) * nChunks];
    const int count = next - base;
    const int nodeBase = b * NPB;
    const int nNodes = min(NPB, M_NODES - nodeBase);
    cnt[t] = 0;
    cnt[t + 256] = 0;
    __syncthreads();
    for (int i = t; i < count; i += 256)
        atomicAdd(&cnt[pairs[base + i].x - nodeBase], 1);
    __syncthreads();
    scn[t] = cnt[t];
    scn[t + 256] = cnt[t + 256];
    __syncthreads();
#pragma unroll
    for (int o = 1; o < 512; o <<= 1) {
        int a0 = (t >= o) ? scn[t - o] : 0;
        int a1 = scn[t + 256 - o];  // t+256 >= o always (o <= 256)
        __syncthreads();
        scn[t] += a0;
        scn[t + 256] += a1;
        __syncthreads();
    }
    int o0 = scn[t] - cnt[t];          // exclusive offsets (node-local)
    int o1 = scn[t + 256] - cnt[t + 256];
    __syncthreads();
    cnt[t] = o0;                        // cnt[] becomes fill cursor
    cnt[t + 256] = o1;
    if (t < nNodes) rowptr[nodeBase + t] = base + o0;
    if (t + 256 < nNodes) rowptr[nodeBase + t + 256] = base + o1;
    if (b == 0 && t == 0) rowptr[M_NODES] = nE;
    __syncthreads();
    const bool inLds = (count <= BKT_CAP);
    for (int i = t; i < count; i += 256) {
        int2 p = pairs[base + i];
        int pos = atomicAdd(&cnt[p.x - nodeBase], 1);
        if (inLds) sl[pos] = p.y;
        else srcs[base + pos] = p.y;
    }
    __syncthreads();
    if (inLds)
        for (int i = t; i < count; i += 256) srcs[base + i] = sl[i];
}

// ---------------------------------------------------------------------------
// Gather aggregation: bf16 in, f32 accumulate, f32 out.
__global__ void k_gather(const ushort* __restrict__ h,
                         const int* __restrict__ rowptr,
                         const int* __restrict__ srcs,
                         const float* __restrict__ scale,
                         const float* __restrict__ shift,
                         float* __restrict__ agg, int M) {
    int t = threadIdx.x;
    int node = blockIdx.x * 8 + (t >> 5);
    if (node >= M) return;
    int c = (t & 31) * 4;
    const bool bn = (scale != nullptr);
    float4 sc = make_float4(1.f, 1.f, 1.f, 1.f);
    float4 sh = make_float4(0.f, 0.f, 0.f, 0.f);
    if (bn) {
        sc = *(const float4*)(scale + c);
        sh = *(const float4*)(shift + c);
    }
    int beg = rowptr[node];
    int end = rowptr[node + 1];

    uint2 v = *(const uint2*)(h + (size_t)node * DIM + c);
    float a0 = bflo(v.x), a1 = bfhi(v.x), a2 = bflo(v.y), a3 = bfhi(v.y);
    if (bn) {
        a0 = fmaxf(fmaf(a0, sc.x, sh.x), 0.f);
        a1 = fmaxf(fmaf(a1, sc.y, sh.y), 0.f);
        a2 = fmaxf(fmaf(a2, sc.z, sh.z), 0.f);
        a3 = fmaxf(fmaf(a3, sc.w, sh.w), 0.f);
    }
    float b0 = 0.f, b1 = 0.f, b2 = 0.f, b3 = 0.f;

    int j = beg;
    for (; j + 4 <= end; j += 4) {
        int s0 = srcs[j], s1 = srcs[j + 1], s2 = srcs[j + 2], s3 = srcs[j + 3];
        uint2 g0 = *(const uint2*)(h + (size_t)s0 * DIM + c);
        uint2 g1 = *(const uint2*)(h + (size_t)s1 * DIM + c);
        uint2 g2 = *(const uint2*)(h + (size_t)s2 * DIM + c);
        uint2 g3 = *(const uint2*)(h + (size_t)s3 * DIM + c);
        float f0, f1, f2, f3;
        if (bn) {
            f0 = fmaxf(fmaf(bflo(g0.x), sc.x, sh.x), 0.f);
            f1 = fmaxf(fmaf(bfhi(g0.x), sc.y, sh.y), 0.f);
            f2 = fmaxf(fmaf(bflo(g0.y), sc.z, sh.z), 0.f);
            f3 = fmaxf(fmaf(bfhi(g0.y), sc.w, sh.w), 0.f);
            a0 += f0; a1 += f1; a2 += f2; a3 += f3;
            f0 = fmaxf(fmaf(bflo(g1.x), sc.x, sh.x), 0.f);
            f1 = fmaxf(fmaf(bfhi(g1.x), sc.y, sh.y), 0.f);
            f2 = fmaxf(fmaf(bflo(g1.y), sc.z, sh.z), 0.f);
            f3 = fmaxf(fmaf(bfhi(g1.y), sc.w, sh.w), 0.f);
            b0 += f0; b1 += f1; b2 += f2; b3 += f3;
            f0 = fmaxf(fmaf(bflo(g2.x), sc.x, sh.x), 0.f);
            f1 = fmaxf(fmaf(bfhi(g2.x), sc.y, sh.y), 0.f);
            f2 = fmaxf(fmaf(bflo(g2.y), sc.z, sh.z), 0.f);
            f3 = fmaxf(fmaf(bfhi(g2.y), sc.w, sh.w), 0.f);
            a0 += f0; a1 += f1; a2 += f2; a3 += f3;
            f0 = fmaxf(fmaf(bflo(g3.x), sc.x, sh.x), 0.f);
            f1 = fmaxf(fmaf(bfhi(g3.x), sc.y, sh.y), 0.f);
            f2 = fmaxf(fmaf(bflo(g3.y), sc.z, sh.z), 0.f);
            f3 = fmaxf(fmaf(bfhi(g3.y), sc.w, sh.w), 0.f);
            b0 += f0; b1 += f1; b2 += f2; b3 += f3;
        } else {
            a0 += bflo(g0.x); a1 += bfhi(g0.x); a2 += bflo(g0.y); a3 += bfhi(g0.y);
            b0 += bflo(g1.x); b1 += bfhi(g1.x); b2 += bflo(g1.y); b3 += bfhi(g1.y);
            a0 += bflo(g2.x); a1 += bfhi(g2.x); a2 += bflo(g2.y); a3 += bfhi(g2.y);
            b0 += bflo(g3.x); b1 += bfhi(g3.x); b2 += bflo(g3.y); b3 += bfhi(g3.y);
        }
    }
    for (; j < end; ++j) {
        int s = srcs[j];
        uint2 g = *(const uint2*)(h + (size_t)s * DIM + c);
        if (bn) {
            a0 += fmaxf(fmaf(bflo(g.x), sc.x, sh.x), 0.f);
            a1 += fmaxf(fmaf(bfhi(g.x), sc.y, sh.y), 0.f);
            a2 += fmaxf(fmaf(bflo(g.y), sc.z, sh.z), 0.f);
            a3 += fmaxf(fmaf(bfhi(g.y), sc.w, sh.w), 0.f);
        } else {
            a0 += bflo(g.x); a1 += bfhi(g.x); a2 += bflo(g.y); a3 += bfhi(g.y);
        }
    }
    float4 r = make_float4(a0 + b0, a1 + b1, a2 + b2, a3 + b3);
    *(float4*)(agg + (size_t)node * DIM + c) = r;
}

// ---------------------------------------------------------------------------
// Split-bf16 MFMA GEMM (near-f32), LDS-FREE: each wave owns 32 rows x 128
// cols; A fragments are loaded per-lane straight from global (row l&15,
// k-octet (l>>4)*8 is exactly the MFMA A layout), BN + truncation-split to
// hi/lo bf16 planes in registers.  W fragments stream from L2-resident
// global planes.  No barriers in the main loop -> latency hidden by 3
// blocks/CU instead of LDS-capped 2.
__global__ void __launch_bounds__(256, 3) k_gemm(
    const float* __restrict__ A, const ushort* __restrict__ Wh,
    const ushort* __restrict__ Wl, const float* __restrict__ bias,
    const float* __restrict__ scale, const float* __restrict__ shift,
    float* __restrict__ Cf, ushort* __restrict__ Cb,
    float* __restrict__ statSum, float* __restrict__ statSq,
    float* __restrict__ outF, int M) {
    __shared__ float red[1024];  // stats cross-wave reduce only (4 KB)

    const int t = threadIdx.x;
    const int w = t >> 6;
    const int lane = t & 63;
    const int rquad = lane >> 4;
    const int rcol = lane & 15;
    const int rowBase = blockIdx.x * 128;

    f32x4 acc[2][8];
#pragma unroll
    for (int i = 0; i < 2; ++i)
#pragma unroll
        for (int j = 0; j < 8; ++j) acc[i][j] = (f32x4){0.f, 0.f, 0.f, 0.f};

#pragma unroll
    for (int kc = 0; kc < 4; ++kc) {
        const int k0 = kc * 32 + rquad * 8;
        // ---- A fragments: direct global load + BN + hi/lo split ----
        bf16x8 ah[2], al[2];
#pragma unroll
        for (int i = 0; i < 2; ++i) {
            int row = rowBase + w * 32 + i * 16 + rcol;
            if (row >= M) row = M - 1;
            const float* ap = A + (size_t)row * DIM + k0;
            float4 p = *(const float4*)ap;
            float4 q = *(const float4*)(ap + 4);
            float f[8] = {p.x, p.y, p.z, p.w, q.x, q.y, q.z, q.w};
            if (scale) {
                float4 s0 = *(const float4*)(scale + k0);
                float4 s1 = *(const float4*)(scale + k0 + 4);
                float4 h0 = *(const float4*)(shift + k0);
                float4 h1 = *(const float4*)(shift + k0 + 4);
                f[0] = fmaxf(fmaf(f[0], s0.x, h0.x), 0.f);
                f[1] = fmaxf(fmaf(f[1], s0.y, h0.y), 0.f);
                f[2] = fmaxf(fmaf(f[2], s0.z, h0.z), 0.f);
                f[3] = fmaxf(fmaf(f[3], s0.w, h0.w), 0.f);
                f[4] = fmaxf(fmaf(f[4], s1.x, h1.x), 0.f);
                f[5] = fmaxf(fmaf(f[5], s1.y, h1.y), 0.f);
                f[6] = fmaxf(fmaf(f[6], s1.z, h1.z), 0.f);
                f[7] = fmaxf(fmaf(f[7], s1.w, h1.w), 0.f);
            }
            uint uh[4], ul[4];
#pragma unroll
            for (int e = 0; e < 4; ++e) {
                uint u0 = __float_as_uint(f[2 * e]);
                uint u1 = __float_as_uint(f[2 * e + 1]);
                uh[e] = (u0 >> 16) | (u1 & 0xffff0000u);
                float r0 = f[2 * e] - __uint_as_float(u0 & 0xffff0000u);
                float r1 = f[2 * e + 1] - __uint_as_float(u1 & 0xffff0000u);
                ul[e] = (__float_as_uint(r0) >> 16) |
                        (__float_as_uint(r1) & 0xffff0000u);
            }
            uint4 H = make_uint4(uh[0], uh[1], uh[2], uh[3]);
            uint4 L = make_uint4(ul[0], ul[1], ul[2], ul[3]);
            ah[i] = *(bf16x8*)&H;
            al[i] = *(bf16x8*)&L;
        }
        // ---- W fragments from global (L2) + 3-term MFMA ----
#pragma unroll
        for (int j = 0; j < 8; ++j) {
            size_t off = (size_t)(j * 16 + rcol) * DIM + k0;
            bf16x8 bh = *(const bf16x8*)(Wh + off);
            bf16x8 bl = *(const bf16x8*)(Wl + off);
            acc[0][j] = __builtin_amdgcn_mfma_f32_16x16x32_bf16(ah[0], bh, acc[0][j], 0, 0, 0);
            acc[1][j] = __builtin_amdgcn_mfma_f32_16x16x32_bf16(ah[1], bh, acc[1][j], 0, 0, 0);
            acc[0][j] = __builtin_amdgcn_mfma_f32_16x16x32_bf16(al[0], bh, acc[0][j], 0, 0, 0);
            acc[1][j] = __builtin_amdgcn_mfma_f32_16x16x32_bf16(al[1], bh, acc[1][j], 0, 0, 0);
            acc[0][j] = __builtin_amdgcn_mfma_f32_16x16x32_bf16(ah[0], bl, acc[0][j], 0, 0, 0);
            acc[1][j] = __builtin_amdgcn_mfma_f32_16x16x32_bf16(ah[1], bl, acc[1][j], 0, 0, 0);
        }
    }

    // ---- epilogue ----
    float bc[8];
#pragma unroll
    for (int j = 0; j < 8; ++j) bc[j] = bias[j * 16 + rcol];

    if (outF) {  // fused L2 normalize
#pragma unroll
        for (int i = 0; i < 2; ++i) {
#pragma unroll
            for (int r = 0; r < 4; ++r) {
                int row = rowBase + w * 32 + i * 16 + rquad * 4 + r;
                float o[8];
                float ss = 0.f;
#pragma unroll
                for (int j = 0; j < 8; ++j) {
                    o[j] = acc[i][j][r] + bc[j];
                    ss += o[j] * o[j];
                }
                ss += __shfl_xor(ss, 1);
                ss += __shfl_xor(ss, 2);
                ss += __shfl_xor(ss, 4);
                ss += __shfl_xor(ss, 8);
                float inv = 1.f / fmaxf(sqrtf(ss), 1e-12f);
                if (row < M) {
#pragma unroll
                    for (int j = 0; j < 8; ++j)
                        outF[(size_t)row * DIM + j * 16 + rcol] = o[j] * inv;
                }
            }
        }
        return;
    }

    // stats mode: store (f32 or bf16) + column sum/sumsq
    float csum[8], csq[8];
#pragma unroll
    for (int j = 0; j < 8; ++j) { csum[j] = 0.f; csq[j] = 0.f; }
#pragma unroll
    for (int i = 0; i < 2; ++i) {
#pragma unroll
        for (int r = 0; r < 4; ++r) {
            int row = rowBase + w * 32 + i * 16 + rquad * 4 + r;
            if (row < M) {
#pragma unroll
                for (int j = 0; j < 8; ++j) {
                    float o = acc[i][j][r] + bc[j];
                    if (Cf) Cf[(size_t)row * DIM + j * 16 + rcol] = o;
                    else Cb[(size_t)row * DIM + j * 16 + rcol] = f2bf(o);
                    csum[j] += o;
                    csq[j] += o * o;
                }
            }
        }
    }
#pragma unroll
    for (int j = 0; j < 8; ++j) {
        csum[j] += __shfl_xor(csum[j], 16);
        csum[j] += __shfl_xor(csum[j], 32);
        csq[j] += __shfl_xor(csq[j], 16);
        csq[j] += __shfl_xor(csq[j], 32);
    }
    if (lane < 16) {
#pragma unroll
        for (int j = 0; j < 8; ++j) {
            red[w * 128 + j * 16 + rcol] = csum[j];
            red[512 + w * 128 + j * 16 + rcol] = csq[j];
        }
    }
    __syncthreads();
    if (t < 128) {
        float s = red[t] + red[128 + t] + red[256 + t] + red[384 + t];
        float q = red[512 + t] + red[640 + t] + red[768 + t] + red[896 + t];
        atomicAdd(statSum + t, s);
        atomicAdd(statSq + t, q);
    }
}

// ---------------------------------------------------------------------------
// Consumes sum/sq -> scale/shift, then ZEROES sum/sq for the next GEMM.
__global__ void k_bnfin(float* __restrict__ sum, float* __restrict__ sq,
                        const float* __restrict__ g,
                        const float* __restrict__ be,
                        float* __restrict__ scale,
                        float* __restrict__ shift, float invN) {
    int c = threadIdx.x;
    float mu = sum[c] * invN;
    float var = sq[c] * invN - mu * mu;
    float inv = rsqrtf(var + 1e-5f);
    float s = g[c] * inv;
    scale[c] = s;
    shift[c] = be[c] - mu * s;
    sum[c] = 0.f;
    sq[c] = 0.f;
}

// ---------------------------------------------------------------------------
extern "C" void kernel_launch(void* const* d_in, const int* in_sizes, int n_in,
                              void* d_out, int out_size, void* d_ws,
                              size_t ws_size, hipStream_t stream) {
    const float* x = (const float*)d_in[0];
    const int* ei = (const int*)d_in[1];
    const float* W1 = (const float*)d_in[2];
    const float* b1 = (const float*)d_in[3];
    const float* g1 = (const float*)d_in[4];
    const float* be1 = (const float*)d_in[5];
    const float* W2 = (const float*)d_in[6];
    const float* b2 = (const float*)d_in[7];
    const float* g_out = (const float*)d_in[8];
    const float* b_out = (const float*)d_in[9];
    float* out = (float*)d_out;

    const int M = M_NODES;
    const int E = N_EDGES_TOT;
    const size_t NM = (size_t)M * DIM;
    const int nChunks = (E + 2047) / 2048;          // 782
    const int nMat = NBKT * nChunks;                // 200192 (multiple of 256)

    float* AGC = (float*)d_ws;         // f32: gather out / GEMM1 in-place out
    ushort* B0 = (ushort*)(AGC + NM);  // bf16 h buffer (gather input)
    ushort* Wh = B0 + NM;              // 6*16384 bf16 hi
    ushort* Wl = Wh + 6 * 16384;       // 6*16384 bf16 lo
    float* st = (float*)(Wl + 6 * 16384);
    float* sum = st;
    float* sq = st + 128;
    float* sc1 = st + 256;
    float* sh1 = st + 384;
    float* sc2 = st + 512;
    float* sh2 = st + 640;
    int2* pairs = (int2*)(st + 768);   // E int2
    int* rowptr = (int*)(pairs + E);   // M+1
    int* cntM = rowptr + (M + 2);      // nMat
    int* bsum = cntM + nMat;           // 1024
    int* srcs = bsum + 1024;           // E

    const int* src = ei;
    const int* dst = ei + E;

    const int gemmGrid = (M + 127) / 128;
    const int gathGrid = (M + 7) / 8;
    const float invN = 1.f / (float)M;

    // ---------------- CSR build (bucket radix, no global atomics) ------
    k_bhist<<<nChunks, 256, 0, stream>>>(dst, cntM, E, nChunks);
    k_scanA<<<nMat / 256, 256, 0, stream>>>(cntM, bsum, nMat);
    k_scanB<<<1, 1024, 0, stream>>>(bsum, nMat / 256);
    k_scanC<<<nMat / 256, 256, 0, stream>>>(cntM, bsum);
    k_pairs<<<nChunks, 256, 0, stream>>>(src, dst, cntM, pairs, E, nChunks);
    k_csrD<<<NBKT, 256, 0, stream>>>(pairs, cntM, nChunks, rowptr, srcs, E);

    // ---------------- prep conversions ---------------------------------
    k_cvt<<<(int)((NM / 4 + 255) / 256), 256, 0, stream>>>(x, B0, (int)(NM / 4));
    k_wprep<<<(6 * 16384 + 255) / 256, 256, 0, stream>>>(W1, W2, Wh, Wl);
    k_zerof<<<1, 256, 0, stream>>>(sum, 256);  // sum+sq; bnfin re-zeroes after

    // ---------------- layer 0 ----------------
    k_gather<<<gathGrid, 256, 0, stream>>>(B0, rowptr, srcs, nullptr, nullptr, AGC, M);
    k_gemm<<<gemmGrid, 256, 0, stream>>>(AGC, Wh, Wl, b1, nullptr, nullptr,
                                         AGC, nullptr, sum, sq, nullptr, M);
    k_bnfin<<<1, 128, 0, stream>>>(sum, sq, g1, be1, sc1, sh1, invN);
    k_gemm<<<gemmGrid, 256, 0, stream>>>(AGC, Wh + 3 * 16384, Wl + 3 * 16384, b2,
                                         sc1, sh1, nullptr, B0, sum, sq, nullptr, M);
    k_bnfin<<<1, 128, 0, stream>>>(sum, sq, g_out, b_out, sc2, sh2, invN);

    // ---------------- layer 1 ----------------
    k_gather<<<gathGrid, 256, 0, stream>>>(B0, rowptr, srcs, sc2, sh2, AGC, M);
    k_gemm<<<gemmGrid, 256, 0, stream>>>(AGC, Wh + 16384, Wl + 16384, b1 + 128,
                                         nullptr, nullptr, AGC, nullptr, sum, sq, nullptr, M);
    k_bnfin<<<1, 128, 0, stream>>>(sum, sq, g1 + 128, be1 + 128, sc1, sh1, invN);
    k_gemm<<<gemmGrid, 256, 0, stream>>>(AGC, Wh + 4 * 16384, Wl + 4 * 16384, b2 + 128,
                                         sc1, sh1, nullptr, B0, sum, sq, nullptr, M);
    k_bnfin<<<1, 128, 0, stream>>>(sum, sq, g_out + 128, b_out + 128, sc2, sh2, invN);

    // ---------------- layer 2 ----------------
    k_gather<<<gathGrid, 256, 0, stream>>>(B0, rowptr, srcs, sc2, sh2, AGC, M);
    k_gemm<<<gemmGrid, 256, 0, stream>>>(AGC, Wh + 2 * 16384, Wl + 2 * 16384, b1 + 256,
                                         nullptr, nullptr, AGC, nullptr, sum, sq, nullptr, M);
    k_bnfin<<<1, 128, 0, stream>>>(sum, sq, g1 + 256, be1 + 256, sc1, sh1, invN);
    // final GEMM: fused L2 normalize, f32 straight to d_out
    k_gemm<<<gemmGrid, 256, 0, stream>>>(AGC, Wh + 5 * 16384, Wl + 5 * 16384, b2 + 256,
                                         sc1, sh1, nullptr, nullptr, nullptr, nullptr, out, M);
}

// Round 9
// 585.694 us; speedup vs baseline: 1.1344x; 1.1344x over previous
//
#include <hip/hip_runtime.h>

#define M_NODES 100000
#define PADM 100032   // 1563 * 64, padded row count for GEMM planes
#define DIM 128
#define N_EDGES_TOT 1600000
#define NBKT 256
#define NPB 391
#define BKT_CAP 8192

typedef unsigned int uint;
typedef unsigned short ushort;
typedef __attribute__((ext_vector_type(8))) short bf16x8;
typedef __attribute__((ext_vector_type(4))) float f32x4;

__device__ __forceinline__ float bflo(uint u) { return __uint_as_float(u << 16); }
__device__ __forceinline__ float bfhi(uint u) { return __uint_as_float(u & 0xffff0000u); }
__device__ __forceinline__ float bf2f(ushort h) { return __uint_as_float(((uint)h) << 16); }
__device__ __forceinline__ ushort f2bf(float f) {
    uint u = __float_as_uint(f);
    return (ushort)((u + 0x7fffu + ((u >> 16) & 1u)) >> 16);
}

// ---------------------------------------------------------------------------
__global__ void k_zerof(float* p, int n) {
    int i = blockIdx.x * 256 + threadIdx.x;
    if (i < n) p[i] = 0.f;
}

// x f32 -> bf16 (B0 plane)
__global__ void k_cvt(const float* __restrict__ x, ushort* __restrict__ xb,
                      int n4) {
    int i = blockIdx.x * 256 + threadIdx.x;
    if (i >= n4) return;
    float4 v = ((const float4*)x)[i];
    uint2 r;
    r.x = (uint)f2bf(v.x) | ((uint)f2bf(v.y) << 16);
    r.y = (uint)f2bf(v.z) | ((uint)f2bf(v.w) << 16);
    ((uint2*)xb)[i] = r;
}

// W (K x N f32) -> transposed split planes Wh/Wl (N x K bf16), 6 matrices.
__global__ void k_wprep(const float* __restrict__ W1,
                        const float* __restrict__ W2, ushort* __restrict__ Wh,
                        ushort* __restrict__ Wl) {
    int i = blockIdx.x * 256 + threadIdx.x;
    if (i >= 6 * 16384) return;
    int l = i >> 14;
    int r = i & 16383;
    int n = r >> 7, k = r & 127;
    const float* W = (l < 3) ? (W1 + l * 16384) : (W2 + (l - 3) * 16384);
    float w = W[k * 128 + n];
    ushort h = f2bf(w);
    Wh[i] = h;
    Wl[i] = f2bf(w - bf2f(h));
}

// ---------------------------------------------------------------------------
// CSR build, bucket-radix, no global atomics (unchanged from R7).
__global__ void k_bhist(const int* __restrict__ dst, int* __restrict__ cntM,
                        int nE, int nChunks) {
    __shared__ int h[NBKT];
    const int chunk = blockIdx.x, t = threadIdx.x;
    h[t] = 0;
    __syncthreads();
    const int e0 = chunk * 2048;
#pragma unroll
    for (int k = 0; k < 8; ++k) {
        int e = e0 + k * 256 + t;
        if (e < nE) atomicAdd(&h[dst[e] / NPB], 1);
    }
    __syncthreads();
    cntM[t * nChunks + chunk] = h[t];
}

__global__ void k_scanA(int* __restrict__ cnt, int* __restrict__ bsum, int n) {
    __shared__ int s[256];
    int t = threadIdx.x, i = blockIdx.x * 256 + t;
    int v = (i < n) ? cnt[i] : 0;
    s[t] = v;
    __syncthreads();
#pragma unroll
    for (int o = 1; o < 256; o <<= 1) {
        int a = (t >= o) ? s[t - o] : 0;
        __syncthreads();
        s[t] += a;
        __syncthreads();
    }
    if (i < n) cnt[i] = s[t] - v;
    if (t == 255) bsum[blockIdx.x] = s[255];
}

__global__ void k_scanB(int* bsum, int nB) {
    __shared__ int s[1024];
    int t = threadIdx.x;
    int v = (t < nB) ? bsum[t] : 0;
    s[t] = v;
    __syncthreads();
#pragma unroll
    for (int o = 1; o < 1024; o <<= 1) {
        int a = (t >= o) ? s[t - o] : 0;
        __syncthreads();
        s[t] += a;
        __syncthreads();
    }
    if (t < nB) bsum[t] = s[t] - v;
}

__global__ void k_scanC(int* __restrict__ excl, const int* __restrict__ bsum) {
    int i = blockIdx.x * 256 + threadIdx.x;
    excl[i] += bsum[blockIdx.x];
}

__global__ void k_pairs(const int* __restrict__ src, const int* __restrict__ dst,
                        const int* __restrict__ exclM, int2* __restrict__ pairs,
                        int nE, int nChunks) {
    __shared__ int base[NBKT];
    const int chunk = blockIdx.x, t = threadIdx.x;
    base[t] = exclM[t * nChunks + chunk];
    __syncthreads();
    const int e0 = chunk * 2048;
#pragma unroll
    for (int k = 0; k < 8; ++k) {
        int e = e0 + k * 256 + t;
        if (e < nE) {
            int d = dst[e];
            int pos = atomicAdd(&base[d / NPB], 1);
            pairs[pos] = make_int2(d, src[e]);
        }
    }
}

__global__ void k_csrD(const int2* __restrict__ pairs,
                       const int* __restrict__ exclM, int nChunks,
                       int* __restrict__ rowptr, int* __restrict__ srcs,
                       int nE) {
    __shared__ int cnt[512];
    __shared__ int scn[512];
    __shared__ int sl[BKT_CAP];
    const int b = blockIdx.x, t = threadIdx.x;
    const int base = exclM[b * nChunks];
    const int next = (b == NBKT - 1) ? nE : exclM[(b + 1) * nChunks];
    const int count = next - base;
    const int nodeBase = b * NPB;
    const int nNodes = min(NPB, M_NODES - nodeBase);
    cnt[t] = 0;
    cnt[t + 256] = 0;
    __syncthreads();
    for (int i = t; i < count; i += 256)
        atomicAdd(&cnt[pairs[base + i].x - nodeBase], 1);
    __syncthreads();
    scn[t] = cnt[t];
    scn[t + 256] = cnt[t + 256];
    __syncthreads();
#pragma unroll
    for (int o = 1; o < 512; o <<= 1) {
        int a0 = (t >= o) ? scn[t - o] : 0;
        int a1 = scn[t + 256 - o];
        __syncthreads();
        scn[t] += a0;
        scn[t + 256] += a1;
        __syncthreads();
    }
    int o0 = scn[t] - cnt[t];
    int o1 = scn[t + 256] - cnt[t + 256];
    __syncthreads();
    cnt[t] = o0;
    cnt[t + 256] = o1;
    if (t < nNodes) rowptr[nodeBase + t] = base + o0;
    if (t + 256 < nNodes) rowptr[nodeBase + t + 256] = base + o1;
    if (b == 0 && t == 0) rowptr[M_NODES] = nE;
    __syncthreads();
    const bool inLds = (count <= BKT_CAP);
    for (int i = t; i < count; i += 256) {
        int2 p = pairs[base + i];
        int pos = atomicAdd(&cnt[p.x - nodeBase], 1);
        if (inLds) sl[pos] = p.y;
        else srcs[base + pos] = p.y;
    }
    __syncthreads();
    if (inLds)
        for (int i = t; i < count; i += 256) srcs[base + i] = sl[i];
}

// ---------------------------------------------------------------------------
// Gather: bf16 in, f32 accumulate, writes SPLIT hi/lo bf16 planes.
__global__ void k_gather(const ushort* __restrict__ h,
                         const int* __restrict__ rowptr,
                         const int* __restrict__ srcs,
                         const float* __restrict__ scale,
                         const float* __restrict__ shift,
                         ushort* __restrict__ AGh, ushort* __restrict__ AGl,
                         int M) {
    int t = threadIdx.x;
    int node = blockIdx.x * 8 + (t >> 5);
    if (node >= M) return;
    int c = (t & 31) * 4;
    const bool bn = (scale != nullptr);
    float4 sc = make_float4(1.f, 1.f, 1.f, 1.f);
    float4 sh = make_float4(0.f, 0.f, 0.f, 0.f);
    if (bn) {
        sc = *(const float4*)(scale + c);
        sh = *(const float4*)(shift + c);
    }
    int beg = rowptr[node];
    int end = rowptr[node + 1];

    uint2 v = *(const uint2*)(h + (size_t)node * DIM + c);
    float a0 = bflo(v.x), a1 = bfhi(v.x), a2 = bflo(v.y), a3 = bfhi(v.y);
    if (bn) {
        a0 = fmaxf(fmaf(a0, sc.x, sh.x), 0.f);
        a1 = fmaxf(fmaf(a1, sc.y, sh.y), 0.f);
        a2 = fmaxf(fmaf(a2, sc.z, sh.z), 0.f);
        a3 = fmaxf(fmaf(a3, sc.w, sh.w), 0.f);
    }
    float b0 = 0.f, b1 = 0.f, b2 = 0.f, b3 = 0.f;

    int j = beg;
    for (; j + 4 <= end; j += 4) {
        int s0 = srcs[j], s1 = srcs[j + 1], s2 = srcs[j + 2], s3 = srcs[j + 3];
        uint2 g0 = *(const uint2*)(h + (size_t)s0 * DIM + c);
        uint2 g1 = *(const uint2*)(h + (size_t)s1 * DIM + c);
        uint2 g2 = *(const uint2*)(h + (size_t)s2 * DIM + c);
        uint2 g3 = *(const uint2*)(h + (size_t)s3 * DIM + c);
        if (bn) {
            a0 += fmaxf(fmaf(bflo(g0.x), sc.x, sh.x), 0.f);
            a1 += fmaxf(fmaf(bfhi(g0.x), sc.y, sh.y), 0.f);
            a2 += fmaxf(fmaf(bflo(g0.y), sc.z, sh.z), 0.f);
            a3 += fmaxf(fmaf(bfhi(g0.y), sc.w, sh.w), 0.f);
            b0 += fmaxf(fmaf(bflo(g1.x), sc.x, sh.x), 0.f);
            b1 += fmaxf(fmaf(bfhi(g1.x), sc.y, sh.y), 0.f);
            b2 += fmaxf(fmaf(bflo(g1.y), sc.z, sh.z), 0.f);
            b3 += fmaxf(fmaf(bfhi(g1.y), sc.w, sh.w), 0.f);
            a0 += fmaxf(fmaf(bflo(g2.x), sc.x, sh.x), 0.f);
            a1 += fmaxf(fmaf(bfhi(g2.x), sc.y, sh.y), 0.f);
            a2 += fmaxf(fmaf(bflo(g2.y), sc.z, sh.z), 0.f);
            a3 += fmaxf(fmaf(bfhi(g2.y), sc.w, sh.w), 0.f);
            b0 += fmaxf(fmaf(bflo(g3.x), sc.x, sh.x), 0.f);
            b1 += fmaxf(fmaf(bfhi(g3.x), sc.y, sh.y), 0.f);
            b2 += fmaxf(fmaf(bflo(g3.y), sc.z, sh.z), 0.f);
            b3 += fmaxf(fmaf(bfhi(g3.y), sc.w, sh.w), 0.f);
        } else {
            a0 += bflo(g0.x); a1 += bfhi(g0.x); a2 += bflo(g0.y); a3 += bfhi(g0.y);
            b0 += bflo(g1.x); b1 += bfhi(g1.x); b2 += bflo(g1.y); b3 += bfhi(g1.y);
            a0 += bflo(g2.x); a1 += bfhi(g2.x); a2 += bflo(g2.y); a3 += bfhi(g2.y);
            b0 += bflo(g3.x); b1 += bfhi(g3.x); b2 += bflo(g3.y); b3 += bfhi(g3.y);
        }
    }
    for (; j < end; ++j) {
        int s = srcs[j];
        uint2 g = *(const uint2*)(h + (size_t)s * DIM + c);
        if (bn) {
            a0 += fmaxf(fmaf(bflo(g.x), sc.x, sh.x), 0.f);
            a1 += fmaxf(fmaf(bfhi(g.x), sc.y, sh.y), 0.f);
            a2 += fmaxf(fmaf(bflo(g.y), sc.z, sh.z), 0.f);
            a3 += fmaxf(fmaf(bfhi(g.y), sc.w, sh.w), 0.f);
        } else {
            a0 += bflo(g.x); a1 += bfhi(g.x); a2 += bflo(g.y); a3 += bfhi(g.y);
        }
    }
    float s0 = a0 + b0, s1 = a1 + b1, s2 = a2 + b2, s3 = a3 + b3;
    ushort h0 = f2bf(s0), h1 = f2bf(s1), h2 = f2bf(s2), h3 = f2bf(s3);
    ushort l0 = f2bf(s0 - bf2f(h0)), l1 = f2bf(s1 - bf2f(h1));
    ushort l2 = f2bf(s2 - bf2f(h2)), l3 = f2bf(s3 - bf2f(h3));
    uint2 hp, lp;
    hp.x = (uint)h0 | ((uint)h1 << 16);
    hp.y = (uint)h2 | ((uint)h3 << 16);
    lp.x = (uint)l0 | ((uint)l1 << 16);
    lp.y = (uint)l2 | ((uint)l3 << 16);
    size_t ix = (size_t)node * DIM + c;
    *(uint2*)(AGh + ix) = hp;
    *(uint2*)(AGl + ix) = lp;
}

// ---------------------------------------------------------------------------
// GEMM A-variant: C = (Ah+Al) @ W + bias (no BN in staging).  64-row tile,
// whole K staged once into 32KB swizzled LDS, single barrier, 5 blocks/CU.
// Wave w owns all 64 rows x cols [w*32, w*32+32).  In-place split write +
// column stats.
__global__ void __launch_bounds__(256, 5) k_gemmA(
    ushort* __restrict__ Ah, ushort* __restrict__ Al,
    const ushort* __restrict__ Wh, const ushort* __restrict__ Wl,
    const float* __restrict__ bias, float* __restrict__ statSum,
    float* __restrict__ statSq, int M) {
    __shared__ ushort lds[16384];  // [2 planes][64 rows][128] bf16, swizzled
    const int t = threadIdx.x;
    const int w = t >> 6, lane = t & 63, rq = lane >> 4, rc = lane & 15;
    const int row0 = blockIdx.x * 64;

    // stage both planes (coalesced uint4), swizzle on LDS write
#pragma unroll
    for (int i = 0; i < 8; ++i) {
        int idx = t + i * 256;  // 0..2047 16B-chunks
        int pl = idx >> 10;
        int r = (idx >> 4) & 63;
        int cb = idx & 15;
        const ushort* p = pl ? Al : Ah;
        uint4 v = *(const uint4*)(p + (size_t)(row0 + r) * DIM + cb * 8);
        *(uint4*)((char*)lds + pl * 16384 + r * 256 +
                  ((cb * 16) ^ ((r & 15) << 4))) = v;
    }
    __syncthreads();

    f32x4 acc[4][2];
#pragma unroll
    for (int i = 0; i < 4; ++i)
#pragma unroll
        for (int jj = 0; jj < 2; ++jj) acc[i][jj] = (f32x4){0.f, 0.f, 0.f, 0.f};

#pragma unroll
    for (int kc = 0; kc < 4; ++kc) {
        bf16x8 bh[2], bl[2];
#pragma unroll
        for (int jj = 0; jj < 2; ++jj) {
            size_t off = (size_t)(w * 32 + jj * 16 + rc) * DIM + kc * 32 + rq * 8;
            bh[jj] = *(const bf16x8*)(Wh + off);
            bl[jj] = *(const bf16x8*)(Wl + off);
        }
        const int kb = kc * 64 + rq * 16;
#pragma unroll
        for (int i = 0; i < 4; ++i) {
            int lr = i * 16 + rc;
            int so = lr * 256 + (kb ^ ((lr & 15) << 4));
            bf16x8 ah = *(const bf16x8*)((char*)lds + so);
            bf16x8 al = *(const bf16x8*)((char*)lds + 16384 + so);
#pragma unroll
            for (int jj = 0; jj < 2; ++jj) {
                acc[i][jj] = __builtin_amdgcn_mfma_f32_16x16x32_bf16(ah, bh[jj], acc[i][jj], 0, 0, 0);
                acc[i][jj] = __builtin_amdgcn_mfma_f32_16x16x32_bf16(al, bh[jj], acc[i][jj], 0, 0, 0);
                acc[i][jj] = __builtin_amdgcn_mfma_f32_16x16x32_bf16(ah, bl[jj], acc[i][jj], 0, 0, 0);
            }
        }
    }

    float bc[2] = {bias[w * 32 + rc], bias[w * 32 + 16 + rc]};
    float csum[2] = {0.f, 0.f}, csq[2] = {0.f, 0.f};
#pragma unroll
    for (int i = 0; i < 4; ++i)
#pragma unroll
        for (int r = 0; r < 4; ++r) {
            int row = row0 + i * 16 + rq * 4 + r;
            if (row < M) {
#pragma unroll
                for (int jj = 0; jj < 2; ++jj) {
                    float o = acc[i][jj][r] + bc[jj];
                    ushort hi = f2bf(o);
                    size_t ix = (size_t)row * DIM + w * 32 + jj * 16 + rc;
                    Ah[ix] = hi;
                    Al[ix] = f2bf(o - bf2f(hi));
                    csum[jj] += o;
                    csq[jj] += o * o;
                }
            }
        }
#pragma unroll
    for (int jj = 0; jj < 2; ++jj) {
        csum[jj] += __shfl_xor(csum[jj], 16);
        csum[jj] += __shfl_xor(csum[jj], 32);
        csq[jj] += __shfl_xor(csq[jj], 16);
        csq[jj] += __shfl_xor(csq[jj], 32);
    }
    if (lane < 16) {
        atomicAdd(statSum + w * 32 + rc, csum[0]);
        atomicAdd(statSum + w * 32 + 16 + rc, csum[1]);
        atomicAdd(statSq + w * 32 + rc, csq[0]);
        atomicAdd(statSq + w * 32 + 16 + rc, csq[1]);
    }
}

// ---------------------------------------------------------------------------
// GEMM B-variant: C = BNrelu(Ah+Al) @ W + bias.  Same tile/LDS structure;
// staging reconstructs f32, applies BN+ReLU, re-splits.  Output: bf16 Cb +
// stats, or fused row-L2-normalized f32 outF.
__global__ void __launch_bounds__(256, 4) k_gemmB(
    const ushort* __restrict__ Ah, const ushort* __restrict__ Al,
    const ushort* __restrict__ Wh, const ushort* __restrict__ Wl,
    const float* __restrict__ bias, const float* __restrict__ scale,
    const float* __restrict__ shift, ushort* __restrict__ Cb,
    float* __restrict__ outF, float* __restrict__ statSum,
    float* __restrict__ statSq, int M) {
    __shared__ ushort lds[16384];
    const int t = threadIdx.x;
    const int w = t >> 6, lane = t & 63, rq = lane >> 4, rc = lane & 15;
    const int row0 = blockIdx.x * 64;

    // stage: load both planes, BN+ReLU in f32, re-split, swizzled LDS write
#pragma unroll
    for (int i = 0; i < 4; ++i) {
        int idx = t + i * 256;  // 0..1023
        int r = idx >> 4;
        int cb = idx & 15;
        size_t gix = (size_t)(row0 + r) * DIM + cb * 8;
        uint4 H = *(const uint4*)(Ah + gix);
        uint4 L = *(const uint4*)(Al + gix);
        float4 sA = *(const float4*)(scale + cb * 8);
        float4 sB = *(const float4*)(scale + cb * 8 + 4);
        float4 hA = *(const float4*)(shift + cb * 8);
        float4 hB = *(const float4*)(shift + cb * 8 + 4);
        float sc8[8] = {sA.x, sA.y, sA.z, sA.w, sB.x, sB.y, sB.z, sB.w};
        float sh8[8] = {hA.x, hA.y, hA.z, hA.w, hB.x, hB.y, hB.z, hB.w};
        uint hu[4] = {H.x, H.y, H.z, H.w};
        uint lu[4] = {L.x, L.y, L.z, L.w};
        uint oh[4], ol[4];
#pragma unroll
        for (int e = 0; e < 4; ++e) {
            float v0 = bflo(hu[e]) + bflo(lu[e]);
            float v1 = bfhi(hu[e]) + bfhi(lu[e]);
            v0 = fmaxf(fmaf(v0, sc8[2 * e], sh8[2 * e]), 0.f);
            v1 = fmaxf(fmaf(v1, sc8[2 * e + 1], sh8[2 * e + 1]), 0.f);
            ushort h0 = f2bf(v0), h1 = f2bf(v1);
            oh[e] = (uint)h0 | ((uint)h1 << 16);
            ol[e] = (uint)f2bf(v0 - bf2f(h0)) | ((uint)f2bf(v1 - bf2f(h1)) << 16);
        }
        char* dst = (char*)lds + r * 256 + ((cb * 16) ^ ((r & 15) << 4));
        *(uint4*)dst = make_uint4(oh[0], oh[1], oh[2], oh[3]);
        *(uint4*)(dst + 16384) = make_uint4(ol[0], ol[1], ol[2], ol[3]);
    }
    __syncthreads();

    f32x4 acc[4][2];
#pragma unroll
    for (int i = 0; i < 4; ++i)
#pragma unroll
        for (int jj = 0; jj < 2; ++jj) acc[i][jj] = (f32x4){0.f, 0.f, 0.f, 0.f};

#pragma unroll
    for (int kc = 0; kc < 4; ++kc) {
        bf16x8 bh[2], bl[2];
#pragma unroll
        for (int jj = 0; jj < 2; ++jj) {
            size_t off = (size_t)(w * 32 + jj * 16 + rc) * DIM + kc * 32 + rq * 8;
            bh[jj] = *(const bf16x8*)(Wh + off);
            bl[jj] = *(const bf16x8*)(Wl + off);
        }
        const int kb = kc * 64 + rq * 16;
#pragma unroll
        for (int i = 0; i < 4; ++i) {
            int lr = i * 16 + rc;
            int so = lr * 256 + (kb ^ ((lr & 15) << 4));
            bf16x8 ah = *(const bf16x8*)((char*)lds + so);
            bf16x8 al = *(const bf16x8*)((char*)lds + 16384 + so);
#pragma unroll
            for (int jj = 0; jj < 2; ++jj) {
                acc[i][jj] = __builtin_amdgcn_mfma_f32_16x16x32_bf16(ah, bh[jj], acc[i][jj], 0, 0, 0);
                acc[i][jj] = __builtin_amdgcn_mfma_f32_16x16x32_bf16(al, bh[jj], acc[i][jj], 0, 0, 0);
                acc[i][jj] = __builtin_amdgcn_mfma_f32_16x16x32_bf16(ah, bl[jj], acc[i][jj], 0, 0, 0);
            }
        }
    }

    float bc[2] = {bias[w * 32 + rc], bias[w * 32 + 16 + rc]};

    if (outF) {
        // fold bias into acc, row L2-norm across the 4 waves via LDS
#pragma unroll
        for (int i = 0; i < 4; ++i)
#pragma unroll
            for (int r = 0; r < 4; ++r)
#pragma unroll
                for (int jj = 0; jj < 2; ++jj) acc[i][jj][r] += bc[jj];
        __syncthreads();  // staging LDS reads done everywhere; reuse
        float* nr = (float*)lds;  // [64 rows][4 waves]
#pragma unroll
        for (int i = 0; i < 4; ++i)
#pragma unroll
            for (int r = 0; r < 4; ++r) {
                float ss = acc[i][0][r] * acc[i][0][r] + acc[i][1][r] * acc[i][1][r];
                ss += __shfl_xor(ss, 1);
                ss += __shfl_xor(ss, 2);
                ss += __shfl_xor(ss, 4);
                ss += __shfl_xor(ss, 8);
                if (rc == 0) nr[(i * 16 + rq * 4 + r) * 4 + w] = ss;
            }
        __syncthreads();
#pragma unroll
        for (int i = 0; i < 4; ++i)
#pragma unroll
            for (int r = 0; r < 4; ++r) {
                int lrow = i * 16 + rq * 4 + r;
                float4 q = *(const float4*)(nr + lrow * 4);
                float inv = 1.f / fmaxf(sqrtf(q.x + q.y + q.z + q.w), 1e-12f);
                int row = row0 + lrow;
                if (row < M) {
                    outF[(size_t)row * DIM + w * 32 + rc] = acc[i][0][r] * inv;
                    outF[(size_t)row * DIM + w * 32 + 16 + rc] = acc[i][1][r] * inv;
                }
            }
        return;
    }

    float csum[2] = {0.f, 0.f}, csq[2] = {0.f, 0.f};
#pragma unroll
    for (int i = 0; i < 4; ++i)
#pragma unroll
        for (int r = 0; r < 4; ++r) {
            int row = row0 + i * 16 + rq * 4 + r;
            if (row < M) {
#pragma unroll
                for (int jj = 0; jj < 2; ++jj) {
                    float o = acc[i][jj][r] + bc[jj];
                    Cb[(size_t)row * DIM + w * 32 + jj * 16 + rc] = f2bf(o);
                    csum[jj] += o;
                    csq[jj] += o * o;
                }
            }
        }
#pragma unroll
    for (int jj = 0; jj < 2; ++jj) {
        csum[jj] += __shfl_xor(csum[jj], 16);
        csum[jj] += __shfl_xor(csum[jj], 32);
        csq[jj] += __shfl_xor(csq[jj], 16);
        csq[jj] += __shfl_xor(csq[jj], 32);
    }
    if (lane < 16) {
        atomicAdd(statSum + w * 32 + rc, csum[0]);
        atomicAdd(statSum + w * 32 + 16 + rc, csum[1]);
        atomicAdd(statSq + w * 32 + rc, csq[0]);
        atomicAdd(statSq + w * 32 + 16 + rc, csq[1]);
    }
}

// ---------------------------------------------------------------------------
__global__ void k_bnfin(float* __restrict__ sum, float* __restrict__ sq,
                        const float* __restrict__ g,
                        const float* __restrict__ be,
                        float* __restrict__ scale,
                        float* __restrict__ shift, float invN) {
    int c = threadIdx.x;
    float mu = sum[c] * invN;
    float var = sq[c] * invN - mu * mu;
    float inv = rsqrtf(var + 1e-5f);
    float s = g[c] * inv;
    scale[c] = s;
    shift[c] = be[c] - mu * s;
    sum[c] = 0.f;
    sq[c] = 0.f;
}

// ---------------------------------------------------------------------------
extern "C" void kernel_launch(void* const* d_in, const int* in_sizes, int n_in,
                              void* d_out, int out_size, void* d_ws,
                              size_t ws_size, hipStream_t stream) {
    const float* x = (const float*)d_in[0];
    const int* ei = (const int*)d_in[1];
    const float* W1 = (const float*)d_in[2];
    const float* b1 = (const float*)d_in[3];
    const float* g1 = (const float*)d_in[4];
    const float* be1 = (const float*)d_in[5];
    const float* W2 = (const float*)d_in[6];
    const float* b2 = (const float*)d_in[7];
    const float* g_out = (const float*)d_in[8];
    const float* b_out = (const float*)d_in[9];
    float* out = (float*)d_out;

    const int M = M_NODES;
    const int E = N_EDGES_TOT;
    const size_t NM = (size_t)M * DIM;
    const size_t PM = (size_t)PADM * DIM;
    const int nChunks = (E + 2047) / 2048;
    const int nMat = NBKT * nChunks;

    ushort* AGh = (ushort*)d_ws;       // [PADM][128] bf16 hi plane
    ushort* AGl = AGh + PM;            // lo plane
    ushort* B0 = AGl + PM;             // [M][128] bf16 h buffer
    ushort* Wh = B0 + NM;
    ushort* Wl = Wh + 6 * 16384;
    float* st = (float*)(Wl + 6 * 16384);
    float* sum = st;
    float* sq = st + 128;
    float* sc1 = st + 256;
    float* sh1 = st + 384;
    float* sc2 = st + 512;
    float* sh2 = st + 640;
    int2* pairs = (int2*)(st + 768);
    int* rowptr = (int*)(pairs + E);
    int* cntM = rowptr + (M + 2);
    int* bsum = cntM + nMat;
    int* srcs = bsum + 1024;

    const int* src = ei;
    const int* dst = ei + E;

    const int gemmGrid = PADM / 64;   // 1563
    const int gathGrid = (M + 7) / 8;
    const float invN = 1.f / (float)M;

    // ---------------- CSR build ----------------
    k_bhist<<<nChunks, 256, 0, stream>>>(dst, cntM, E, nChunks);
    k_scanA<<<nMat / 256, 256, 0, stream>>>(cntM, bsum, nMat);
    k_scanB<<<1, 1024, 0, stream>>>(bsum, nMat / 256);
    k_scanC<<<nMat / 256, 256, 0, stream>>>(cntM, bsum);
    k_pairs<<<nChunks, 256, 0, stream>>>(src, dst, cntM, pairs, E, nChunks);
    k_csrD<<<NBKT, 256, 0, stream>>>(pairs, cntM, nChunks, rowptr, srcs, E);

    // ---------------- prep ----------------
    k_cvt<<<(int)((NM / 4 + 255) / 256), 256, 0, stream>>>(x, B0, (int)(NM / 4));
    k_wprep<<<(6 * 16384 + 255) / 256, 256, 0, stream>>>(W1, W2, Wh, Wl);
    k_zerof<<<1, 256, 0, stream>>>(sum, 256);

    // ---------------- layer 0 ----------------
    k_gather<<<gathGrid, 256, 0, stream>>>(B0, rowptr, srcs, nullptr, nullptr, AGh, AGl, M);
    k_gemmA<<<gemmGrid, 256, 0, stream>>>(AGh, AGl, Wh, Wl, b1, sum, sq, M);
    k_bnfin<<<1, 128, 0, stream>>>(sum, sq, g1, be1, sc1, sh1, invN);
    k_gemmB<<<gemmGrid, 256, 0, stream>>>(AGh, AGl, Wh + 3 * 16384, Wl + 3 * 16384,
                                          b2, sc1, sh1, B0, nullptr, sum, sq, M);
    k_bnfin<<<1, 128, 0, stream>>>(sum, sq, g_out, b_out, sc2, sh2, invN);

    // ---------------- layer 1 ----------------
    k_gather<<<gathGrid, 256, 0, stream>>>(B0, rowptr, srcs, sc2, sh2, AGh, AGl, M);
    k_gemmA<<<gemmGrid, 256, 0, stream>>>(AGh, AGl, Wh + 16384, Wl + 16384, b1 + 128, sum, sq, M);
    k_bnfin<<<1, 128, 0, stream>>>(sum, sq, g1 + 128, be1 + 128, sc1, sh1, invN);
    k_gemmB<<<gemmGrid, 256, 0, stream>>>(AGh, AGl, Wh + 4 * 16384, Wl + 4 * 16384,
                                          b2 + 128, sc1, sh1, B0, nullptr, sum, sq, M);
    k_bnfin<<<1, 128, 0, stream>>>(sum, sq, g_out + 128, b_out + 128, sc2, sh2, invN);

    // ---------------- layer 2 ----------------
    k_gather<<<gathGrid, 256, 0, stream>>>(B0, rowptr, srcs, sc2, sh2, AGh, AGl, M);
    k_gemmA<<<gemmGrid, 256, 0, stream>>>(AGh, AGl, Wh + 2 * 16384, Wl + 2 * 16384, b1 + 256, sum, sq, M);
    k_bnfin<<<1, 128, 0, stream>>>(sum, sq, g1 + 256, be1 + 256, sc1, sh1, invN);
    k_gemmB<<<gemmGrid, 256, 0, stream>>>(AGh, AGl, Wh + 5 * 16384, Wl + 5 * 16384,
                                          b2 + 256, sc1, sh1, nullptr, out, nullptr, nullptr, M);
}

// Round 10
// 569.391 us; speedup vs baseline: 1.1669x; 1.0286x over previous
//
#include <hip/hip_runtime.h>

#define M_NODES 100000
#define PADM 100032   // 1563 * 64, padded row count for GEMM planes
#define DIM 128
#define N_EDGES_TOT 1600000
#define NBKT 256
#define NPB 391
#define BKT_CAP 8192
#define INVN 1e-5f    // 1/100000

typedef unsigned int uint;
typedef unsigned short ushort;
typedef __attribute__((ext_vector_type(8))) short bf16x8;
typedef __attribute__((ext_vector_type(4))) float f32x4;

__device__ __forceinline__ float bflo(uint u) { return __uint_as_float(u << 16); }
__device__ __forceinline__ float bfhi(uint u) { return __uint_as_float(u & 0xffff0000u); }
__device__ __forceinline__ float bf2f(ushort h) { return __uint_as_float(((uint)h) << 16); }
__device__ __forceinline__ ushort f2bf(float f) {
    uint u = __float_as_uint(f);
    return (ushort)((u + 0x7fffu + ((u >> 16) & 1u)) >> 16);
}

// ---------------------------------------------------------------------------
__global__ void k_zerof(float* p, int n) {
    int i = blockIdx.x * 256 + threadIdx.x;
    if (i < n) p[i] = 0.f;
}

// x f32 -> bf16 (B0 plane)
__global__ void k_cvt(const float* __restrict__ x, ushort* __restrict__ xb,
                      int n4) {
    int i = blockIdx.x * 256 + threadIdx.x;
    if (i >= n4) return;
    float4 v = ((const float4*)x)[i];
    uint2 r;
    r.x = (uint)f2bf(v.x) | ((uint)f2bf(v.y) << 16);
    r.y = (uint)f2bf(v.z) | ((uint)f2bf(v.w) << 16);
    ((uint2*)xb)[i] = r;
}

// W (K x N f32) -> transposed split planes Wh/Wl (N x K bf16), 6 matrices.
__global__ void k_wprep(const float* __restrict__ W1,
                        const float* __restrict__ W2, ushort* __restrict__ Wh,
                        ushort* __restrict__ Wl) {
    int i = blockIdx.x * 256 + threadIdx.x;
    if (i >= 6 * 16384) return;
    int l = i >> 14;
    int r = i & 16383;
    int n = r >> 7, k = r & 127;
    const float* W = (l < 3) ? (W1 + l * 16384) : (W2 + (l - 3) * 16384);
    float w = W[k * 128 + n];
    ushort h = f2bf(w);
    Wh[i] = h;
    Wl[i] = f2bf(w - bf2f(h));
}

// ---------------------------------------------------------------------------
// CSR build, bucket-radix, no global atomics.
__global__ void k_bhist(const int* __restrict__ dst, int* __restrict__ cntM,
                        int nE, int nChunks) {
    __shared__ int h[NBKT];
    const int chunk = blockIdx.x, t = threadIdx.x;
    h[t] = 0;
    __syncthreads();
    const int e0 = chunk * 2048;
#pragma unroll
    for (int k = 0; k < 8; ++k) {
        int e = e0 + k * 256 + t;
        if (e < nE) atomicAdd(&h[dst[e] / NPB], 1);
    }
    __syncthreads();
    cntM[t * nChunks + chunk] = h[t];
}

__global__ void k_scanA(int* __restrict__ cnt, int* __restrict__ bsum, int n) {
    __shared__ int s[256];
    int t = threadIdx.x, i = blockIdx.x * 256 + t;
    int v = (i < n) ? cnt[i] : 0;
    s[t] = v;
    __syncthreads();
#pragma unroll
    for (int o = 1; o < 256; o <<= 1) {
        int a = (t >= o) ? s[t - o] : 0;
        __syncthreads();
        s[t] += a;
        __syncthreads();
    }
    if (i < n) cnt[i] = s[t] - v;
    if (t == 255) bsum[blockIdx.x] = s[255];
}

__global__ void k_scanB(int* bsum, int nB) {
    __shared__ int s[1024];
    int t = threadIdx.x;
    int v = (t < nB) ? bsum[t] : 0;
    s[t] = v;
    __syncthreads();
#pragma unroll
    for (int o = 1; o < 1024; o <<= 1) {
        int a = (t >= o) ? s[t - o] : 0;
        __syncthreads();
        s[t] += a;
        __syncthreads();
    }
    if (t < nB) bsum[t] = s[t] - v;
}

__global__ void k_scanC(int* __restrict__ excl, const int* __restrict__ bsum) {
    int i = blockIdx.x * 256 + threadIdx.x;
    excl[i] += bsum[blockIdx.x];
}

__global__ void k_pairs(const int* __restrict__ src, const int* __restrict__ dst,
                        const int* __restrict__ exclM, int2* __restrict__ pairs,
                        int nE, int nChunks) {
    __shared__ int base[NBKT];
    const int chunk = blockIdx.x, t = threadIdx.x;
    base[t] = exclM[t * nChunks + chunk];
    __syncthreads();
    const int e0 = chunk * 2048;
#pragma unroll
    for (int k = 0; k < 8; ++k) {
        int e = e0 + k * 256 + t;
        if (e < nE) {
            int d = dst[e];
            int pos = atomicAdd(&base[d / NPB], 1);
            pairs[pos] = make_int2(d, src[e]);
        }
    }
}

__global__ void k_csrD(const int2* __restrict__ pairs,
                       const int* __restrict__ exclM, int nChunks,
                       int* __restrict__ rowptr, int* __restrict__ srcs,
                       int nE) {
    __shared__ int cnt[512];
    __shared__ int scn[512];
    __shared__ int sl[BKT_CAP];
    const int b = blockIdx.x, t = threadIdx.x;
    const int base = exclM[b * nChunks];
    const int next = (b == NBKT - 1) ? nE : exclM[(b + 1) * nChunks];
    const int count = next - base;
    const int nodeBase = b * NPB;
    const int nNodes = min(NPB, M_NODES - nodeBase);
    cnt[t] = 0;
    cnt[t + 256] = 0;
    __syncthreads();
    for (int i = t; i < count; i += 256)
        atomicAdd(&cnt[pairs[base + i].x - nodeBase], 1);
    __syncthreads();
    scn[t] = cnt[t];
    scn[t + 256] = cnt[t + 256];
    __syncthreads();
#pragma unroll
    for (int o = 1; o < 512; o <<= 1) {
        int a0 = (t >= o) ? scn[t - o] : 0;
        int a1 = scn[t + 256 - o];
        __syncthreads();
        scn[t] += a0;
        scn[t + 256] += a1;
        __syncthreads();
    }
    int o0 = scn[t] - cnt[t];
    int o1 = scn[t + 256] - cnt[t + 256];
    __syncthreads();
    cnt[t] = o0;
    cnt[t + 256] = o1;
    if (t < nNodes) rowptr[nodeBase + t] = base + o0;
    if (t + 256 < nNodes) rowptr[nodeBase + t + 256] = base + o1;
    if (b == 0 && t == 0) rowptr[M_NODES] = nE;
    __syncthreads();
    const bool inLds = (count <= BKT_CAP);
    for (int i = t; i < count; i += 256) {
        int2 p = pairs[base + i];
        int pos = atomicAdd(&cnt[p.x - nodeBase], 1);
        if (inLds) sl[pos] = p.y;
        else srcs[base + pos] = p.y;
    }
    __syncthreads();
    if (inLds)
        for (int i = t; i < count; i += 256) srcs[base + i] = sl[i];
}

// ---------------------------------------------------------------------------
// Gather: bf16 in, f32 accumulate, writes SPLIT hi/lo bf16 planes.
// BN coefficients computed inline from producer stats slot (bnstats!=null).
__global__ void k_gather(const ushort* __restrict__ h,
                         const int* __restrict__ rowptr,
                         const int* __restrict__ srcs,
                         const float* __restrict__ bnstats,
                         const float* __restrict__ gamma,
                         const float* __restrict__ beta,
                         ushort* __restrict__ AGh, ushort* __restrict__ AGl,
                         int M) {
    int t = threadIdx.x;
    int node = blockIdx.x * 8 + (t >> 5);
    if (node >= M) return;
    int c = (t & 31) * 4;
    const bool bn = (bnstats != nullptr);
    float4 sc = make_float4(1.f, 1.f, 1.f, 1.f);
    float4 sh = make_float4(0.f, 0.f, 0.f, 0.f);
    if (bn) {
        float4 sum4 = *(const float4*)(bnstats + c);
        float4 sq4 = *(const float4*)(bnstats + 128 + c);
        float4 g4 = *(const float4*)(gamma + c);
        float4 b4 = *(const float4*)(beta + c);
        float mu, var, s;
        mu = sum4.x * INVN; var = sq4.x * INVN - mu * mu;
        s = g4.x * rsqrtf(var + 1e-5f); sc.x = s; sh.x = b4.x - mu * s;
        mu = sum4.y * INVN; var = sq4.y * INVN - mu * mu;
        s = g4.y * rsqrtf(var + 1e-5f); sc.y = s; sh.y = b4.y - mu * s;
        mu = sum4.z * INVN; var = sq4.z * INVN - mu * mu;
        s = g4.z * rsqrtf(var + 1e-5f); sc.z = s; sh.z = b4.z - mu * s;
        mu = sum4.w * INVN; var = sq4.w * INVN - mu * mu;
        s = g4.w * rsqrtf(var + 1e-5f); sc.w = s; sh.w = b4.w - mu * s;
    }
    int beg = rowptr[node];
    int end = rowptr[node + 1];

    uint2 v = *(const uint2*)(h + (size_t)node * DIM + c);
    float a0 = bflo(v.x), a1 = bfhi(v.x), a2 = bflo(v.y), a3 = bfhi(v.y);
    if (bn) {
        a0 = fmaxf(fmaf(a0, sc.x, sh.x), 0.f);
        a1 = fmaxf(fmaf(a1, sc.y, sh.y), 0.f);
        a2 = fmaxf(fmaf(a2, sc.z, sh.z), 0.f);
        a3 = fmaxf(fmaf(a3, sc.w, sh.w), 0.f);
    }
    float b0 = 0.f, b1 = 0.f, b2 = 0.f, b3 = 0.f;

    int j = beg;
    for (; j + 4 <= end; j += 4) {
        int s0 = srcs[j], s1 = srcs[j + 1], s2 = srcs[j + 2], s3 = srcs[j + 3];
        uint2 g0 = *(const uint2*)(h + (size_t)s0 * DIM + c);
        uint2 g1 = *(const uint2*)(h + (size_t)s1 * DIM + c);
        uint2 g2 = *(const uint2*)(h + (size_t)s2 * DIM + c);
        uint2 g3 = *(const uint2*)(h + (size_t)s3 * DIM + c);
        if (bn) {
            a0 += fmaxf(fmaf(bflo(g0.x), sc.x, sh.x), 0.f);
            a1 += fmaxf(fmaf(bfhi(g0.x), sc.y, sh.y), 0.f);
            a2 += fmaxf(fmaf(bflo(g0.y), sc.z, sh.z), 0.f);
            a3 += fmaxf(fmaf(bfhi(g0.y), sc.w, sh.w), 0.f);
            b0 += fmaxf(fmaf(bflo(g1.x), sc.x, sh.x), 0.f);
            b1 += fmaxf(fmaf(bfhi(g1.x), sc.y, sh.y), 0.f);
            b2 += fmaxf(fmaf(bflo(g1.y), sc.z, sh.z), 0.f);
            b3 += fmaxf(fmaf(bfhi(g1.y), sc.w, sh.w), 0.f);
            a0 += fmaxf(fmaf(bflo(g2.x), sc.x, sh.x), 0.f);
            a1 += fmaxf(fmaf(bfhi(g2.x), sc.y, sh.y), 0.f);
            a2 += fmaxf(fmaf(bflo(g2.y), sc.z, sh.z), 0.f);
            a3 += fmaxf(fmaf(bfhi(g2.y), sc.w, sh.w), 0.f);
            b0 += fmaxf(fmaf(bflo(g3.x), sc.x, sh.x), 0.f);
            b1 += fmaxf(fmaf(bfhi(g3.x), sc.y, sh.y), 0.f);
            b2 += fmaxf(fmaf(bflo(g3.y), sc.z, sh.z), 0.f);
            b3 += fmaxf(fmaf(bfhi(g3.y), sc.w, sh.w), 0.f);
        } else {
            a0 += bflo(g0.x); a1 += bfhi(g0.x); a2 += bflo(g0.y); a3 += bfhi(g0.y);
            b0 += bflo(g1.x); b1 += bfhi(g1.x); b2 += bflo(g1.y); b3 += bfhi(g1.y);
            a0 += bflo(g2.x); a1 += bfhi(g2.x); a2 += bflo(g2.y); a3 += bfhi(g2.y);
            b0 += bflo(g3.x); b1 += bfhi(g3.x); b2 += bflo(g3.y); b3 += bfhi(g3.y);
        }
    }
    for (; j < end; ++j) {
        int s = srcs[j];
        uint2 g = *(const uint2*)(h + (size_t)s * DIM + c);
        if (bn) {
            a0 += fmaxf(fmaf(bflo(g.x), sc.x, sh.x), 0.f);
            a1 += fmaxf(fmaf(bfhi(g.x), sc.y, sh.y), 0.f);
            a2 += fmaxf(fmaf(bflo(g.y), sc.z, sh.z), 0.f);
            a3 += fmaxf(fmaf(bfhi(g.y), sc.w, sh.w), 0.f);
        } else {
            a0 += bflo(g.x); a1 += bfhi(g.x); a2 += bflo(g.y); a3 += bfhi(g.y);
        }
    }
    float s0 = a0 + b0, s1 = a1 + b1, s2 = a2 + b2, s3 = a3 + b3;
    ushort h0 = f2bf(s0), h1 = f2bf(s1), h2 = f2bf(s2), h3 = f2bf(s3);
    ushort l0 = f2bf(s0 - bf2f(h0)), l1 = f2bf(s1 - bf2f(h1));
    ushort l2 = f2bf(s2 - bf2f(h2)), l3 = f2bf(s3 - bf2f(h3));
    uint2 hp, lp;
    hp.x = (uint)h0 | ((uint)h1 << 16);
    hp.y = (uint)h2 | ((uint)h3 << 16);
    lp.x = (uint)l0 | ((uint)l1 << 16);
    lp.y = (uint)l2 | ((uint)l3 << 16);
    size_t ix = (size_t)node * DIM + c;
    *(uint2*)(AGh + ix) = hp;
    *(uint2*)(AGl + ix) = lp;
}

// ---------------------------------------------------------------------------
// GEMM A-variant: C = (Ah+Al) @ W + bias.  W fragments PRELOADED to registers
// before the staging barrier (hides L2 latency under staging); 64-row tile,
// 32KB swizzled LDS, single barrier.  In-place split write + column stats.
__global__ void __launch_bounds__(256, 3) k_gemmA(
    ushort* __restrict__ Ah, ushort* __restrict__ Al,
    const ushort* __restrict__ Wh, const ushort* __restrict__ Wl,
    const float* __restrict__ bias, float* __restrict__ statSlot, int M) {
    __shared__ ushort lds[16384];
    const int t = threadIdx.x;
    const int w = t >> 6, lane = t & 63, rq = lane >> 4, rc = lane & 15;
    const int row0 = blockIdx.x * 64;

    // ---- preload all W fragments (16 x bf16x8 = 64 VGPR) ----
    bf16x8 wh[4][2], wl[4][2];
#pragma unroll
    for (int kc = 0; kc < 4; ++kc)
#pragma unroll
        for (int jj = 0; jj < 2; ++jj) {
            size_t off = (size_t)(w * 32 + jj * 16 + rc) * DIM + kc * 32 + rq * 8;
            wh[kc][jj] = *(const bf16x8*)(Wh + off);
            wl[kc][jj] = *(const bf16x8*)(Wl + off);
        }

    // ---- stage both A planes (coalesced uint4), swizzled LDS write ----
#pragma unroll
    for (int i = 0; i < 8; ++i) {
        int idx = t + i * 256;
        int pl = idx >> 10;
        int r = (idx >> 4) & 63;
        int cb = idx & 15;
        const ushort* p = pl ? Al : Ah;
        uint4 v = *(const uint4*)(p + (size_t)(row0 + r) * DIM + cb * 8);
        *(uint4*)((char*)lds + pl * 16384 + r * 256 +
                  ((cb * 16) ^ ((r & 15) << 4))) = v;
    }
    __syncthreads();

    f32x4 acc[4][2];
#pragma unroll
    for (int i = 0; i < 4; ++i)
#pragma unroll
        for (int jj = 0; jj < 2; ++jj) acc[i][jj] = (f32x4){0.f, 0.f, 0.f, 0.f};

#pragma unroll
    for (int kc = 0; kc < 4; ++kc) {
        const int kb = kc * 64 + rq * 16;
#pragma unroll
        for (int i = 0; i < 4; ++i) {
            int lr = i * 16 + rc;
            int so = lr * 256 + (kb ^ ((lr & 15) << 4));
            bf16x8 ah = *(const bf16x8*)((char*)lds + so);
            bf16x8 al = *(const bf16x8*)((char*)lds + 16384 + so);
#pragma unroll
            for (int jj = 0; jj < 2; ++jj) {
                acc[i][jj] = __builtin_amdgcn_mfma_f32_16x16x32_bf16(ah, wh[kc][jj], acc[i][jj], 0, 0, 0);
                acc[i][jj] = __builtin_amdgcn_mfma_f32_16x16x32_bf16(al, wh[kc][jj], acc[i][jj], 0, 0, 0);
                acc[i][jj] = __builtin_amdgcn_mfma_f32_16x16x32_bf16(ah, wl[kc][jj], acc[i][jj], 0, 0, 0);
            }
        }
    }

    float bc[2] = {bias[w * 32 + rc], bias[w * 32 + 16 + rc]};
    float csum[2] = {0.f, 0.f}, csq[2] = {0.f, 0.f};
#pragma unroll
    for (int i = 0; i < 4; ++i)
#pragma unroll
        for (int r = 0; r < 4; ++r) {
            int row = row0 + i * 16 + rq * 4 + r;
            if (row < M) {
#pragma unroll
                for (int jj = 0; jj < 2; ++jj) {
                    float o = acc[i][jj][r] + bc[jj];
                    ushort hi = f2bf(o);
                    size_t ix = (size_t)row * DIM + w * 32 + jj * 16 + rc;
                    Ah[ix] = hi;
                    Al[ix] = f2bf(o - bf2f(hi));
                    csum[jj] += o;
                    csq[jj] += o * o;
                }
            }
        }
#pragma unroll
    for (int jj = 0; jj < 2; ++jj) {
        csum[jj] += __shfl_xor(csum[jj], 16);
        csum[jj] += __shfl_xor(csum[jj], 32);
        csq[jj] += __shfl_xor(csq[jj], 16);
        csq[jj] += __shfl_xor(csq[jj], 32);
    }
    if (lane < 16) {
        atomicAdd(statSlot + w * 32 + rc, csum[0]);
        atomicAdd(statSlot + w * 32 + 16 + rc, csum[1]);
        atomicAdd(statSlot + 128 + w * 32 + rc, csq[0]);
        atomicAdd(statSlot + 128 + w * 32 + 16 + rc, csq[1]);
    }
}

// ---------------------------------------------------------------------------
// GEMM B-variant: C = BNrelu(Ah+Al) @ W + bias.  BN coefs computed inline
// from bnstats slot; W preloaded like gemmA.  Output: bf16 Cb + stats, or
// fused row-L2-normalized f32 outF.
__global__ void __launch_bounds__(256, 3) k_gemmB(
    const ushort* __restrict__ Ah, const ushort* __restrict__ Al,
    const ushort* __restrict__ Wh, const ushort* __restrict__ Wl,
    const float* __restrict__ bias, const float* __restrict__ bnstats,
    const float* __restrict__ gamma, const float* __restrict__ beta,
    ushort* __restrict__ Cb, float* __restrict__ outF,
    float* __restrict__ statSlot, int M) {
    __shared__ ushort lds[16384];
    const int t = threadIdx.x;
    const int w = t >> 6, lane = t & 63, rq = lane >> 4, rc = lane & 15;
    const int row0 = blockIdx.x * 64;

    // ---- preload W fragments ----
    bf16x8 wh[4][2], wl[4][2];
#pragma unroll
    for (int kc = 0; kc < 4; ++kc)
#pragma unroll
        for (int jj = 0; jj < 2; ++jj) {
            size_t off = (size_t)(w * 32 + jj * 16 + rc) * DIM + kc * 32 + rq * 8;
            wh[kc][jj] = *(const bf16x8*)(Wh + off);
            wl[kc][jj] = *(const bf16x8*)(Wl + off);
        }

    // ---- BN coefs for this thread's channel octet (invariant over i) ----
    const int cb = t & 15;
    float sc8[8], sh8[8];
#pragma unroll
    for (int e = 0; e < 8; ++e) {
        int ch = cb * 8 + e;
        float mu = bnstats[ch] * INVN;
        float var = bnstats[128 + ch] * INVN - mu * mu;
        float s = gamma[ch] * rsqrtf(var + 1e-5f);
        sc8[e] = s;
        sh8[e] = beta[ch] - mu * s;
    }

    // ---- stage: load planes, BN+ReLU in f32, re-split, swizzled write ----
#pragma unroll
    for (int i = 0; i < 4; ++i) {
        int idx = t + i * 256;
        int r = idx >> 4;
        size_t gix = (size_t)(row0 + r) * DIM + cb * 8;
        uint4 H = *(const uint4*)(Ah + gix);
        uint4 L = *(const uint4*)(Al + gix);
        uint hu[4] = {H.x, H.y, H.z, H.w};
        uint lu[4] = {L.x, L.y, L.z, L.w};
        uint oh[4], ol[4];
#pragma unroll
        for (int e = 0; e < 4; ++e) {
            float v0 = bflo(hu[e]) + bflo(lu[e]);
            float v1 = bfhi(hu[e]) + bfhi(lu[e]);
            v0 = fmaxf(fmaf(v0, sc8[2 * e], sh8[2 * e]), 0.f);
            v1 = fmaxf(fmaf(v1, sc8[2 * e + 1], sh8[2 * e + 1]), 0.f);
            ushort h0 = f2bf(v0), h1 = f2bf(v1);
            oh[e] = (uint)h0 | ((uint)h1 << 16);
            ol[e] = (uint)f2bf(v0 - bf2f(h0)) | ((uint)f2bf(v1 - bf2f(h1)) << 16);
        }
        char* dst = (char*)lds + r * 256 + ((cb * 16) ^ ((r & 15) << 4));
        *(uint4*)dst = make_uint4(oh[0], oh[1], oh[2], oh[3]);
        *(uint4*)(dst + 16384) = make_uint4(ol[0], ol[1], ol[2], ol[3]);
    }
    __syncthreads();

    f32x4 acc[4][2];
#pragma unroll
    for (int i = 0; i < 4; ++i)
#pragma unroll
        for (int jj = 0; jj < 2; ++jj) acc[i][jj] = (f32x4){0.f, 0.f, 0.f, 0.f};

#pragma unroll
    for (int kc = 0; kc < 4; ++kc) {
        const int kb = kc * 64 + rq * 16;
#pragma unroll
        for (int i = 0; i < 4; ++i) {
            int lr = i * 16 + rc;
            int so = lr * 256 + (kb ^ ((lr & 15) << 4));
            bf16x8 ah = *(const bf16x8*)((char*)lds + so);
            bf16x8 al = *(const bf16x8*)((char*)lds + 16384 + so);
#pragma unroll
            for (int jj = 0; jj < 2; ++jj) {
                acc[i][jj] = __builtin_amdgcn_mfma_f32_16x16x32_bf16(ah, wh[kc][jj], acc[i][jj], 0, 0, 0);
                acc[i][jj] = __builtin_amdgcn_mfma_f32_16x16x32_bf16(al, wh[kc][jj], acc[i][jj], 0, 0, 0);
                acc[i][jj] = __builtin_amdgcn_mfma_f32_16x16x32_bf16(ah, wl[kc][jj], acc[i][jj], 0, 0, 0);
            }
        }
    }

    float bc[2] = {bias[w * 32 + rc], bias[w * 32 + 16 + rc]};

    if (outF) {
#pragma unroll
        for (int i = 0; i < 4; ++i)
#pragma unroll
            for (int r = 0; r < 4; ++r)
#pragma unroll
                for (int jj = 0; jj < 2; ++jj) acc[i][jj][r] += bc[jj];
        __syncthreads();
        float* nr = (float*)lds;  // [64 rows][4 waves]
#pragma unroll
        for (int i = 0; i < 4; ++i)
#pragma unroll
            for (int r = 0; r < 4; ++r) {
                float ss = acc[i][0][r] * acc[i][0][r] + acc[i][1][r] * acc[i][1][r];
                ss += __shfl_xor(ss, 1);
                ss += __shfl_xor(ss, 2);
                ss += __shfl_xor(ss, 4);
                ss += __shfl_xor(ss, 8);
                if (rc == 0) nr[(i * 16 + rq * 4 + r) * 4 + w] = ss;
            }
        __syncthreads();
#pragma unroll
        for (int i = 0; i < 4; ++i)
#pragma unroll
            for (int r = 0; r < 4; ++r) {
                int lrow = i * 16 + rq * 4 + r;
                float4 q = *(const float4*)(nr + lrow * 4);
                float inv = 1.f / fmaxf(sqrtf(q.x + q.y + q.z + q.w), 1e-12f);
                int row = row0 + lrow;
                if (row < M) {
                    outF[(size_t)row * DIM + w * 32 + rc] = acc[i][0][r] * inv;
                    outF[(size_t)row * DIM + w * 32 + 16 + rc] = acc[i][1][r] * inv;
                }
            }
        return;
    }

    float csum[2] = {0.f, 0.f}, csq[2] = {0.f, 0.f};
#pragma unroll
    for (int i = 0; i < 4; ++i)
#pragma unroll
        for (int r = 0; r < 4; ++r) {
            int row = row0 + i * 16 + rq * 4 + r;
            if (row < M) {
#pragma unroll
                for (int jj = 0; jj < 2; ++jj) {
                    float o = acc[i][jj][r] + bc[jj];
                    Cb[(size_t)row * DIM + w * 32 + jj * 16 + rc] = f2bf(o);
                    csum[jj] += o;
                    csq[jj] += o * o;
                }
            }
        }
#pragma unroll
    for (int jj = 0; jj < 2; ++jj) {
        csum[jj] += __shfl_xor(csum[jj], 16);
        csum[jj] += __shfl_xor(csum[jj], 32);
        csq[jj] += __shfl_xor(csq[jj], 16);
        csq[jj] += __shfl_xor(csq[jj], 32);
    }
    if (lane < 16) {
        atomicAdd(statSlot + w * 32 + rc, csum[0]);
        atomicAdd(statSlot + w * 32 + 16 + rc, csum[1]);
        atomicAdd(statSlot + 128 + w * 32 + rc, csq[0]);
        atomicAdd(statSlot + 128 + w * 32 + 16 + rc, csq[1]);
    }
}

// ---------------------------------------------------------------------------
extern "C" void kernel_launch(void* const* d_in, const int* in_sizes, int n_in,
                              void* d_out, int out_size, void* d_ws,
                              size_t ws_size, hipStream_t stream) {
    const float* x = (const float*)d_in[0];
    const int* ei = (const int*)d_in[1];
    const float* W1 = (const float*)d_in[2];
    const float* b1 = (const float*)d_in[3];
    const float* g1 = (const float*)d_in[4];
    const float* be1 = (const float*)d_in[5];
    const float* W2 = (const float*)d_in[6];
    const float* b2 = (const float*)d_in[7];
    const float* g_out = (const float*)d_in[8];
    const float* b_out = (const float*)d_in[9];
    float* out = (float*)d_out;

    const int M = M_NODES;
    const int E = N_EDGES_TOT;
    const size_t NM = (size_t)M * DIM;
    const size_t PM = (size_t)PADM * DIM;
    const int nChunks = (E + 2047) / 2048;
    const int nMat = NBKT * nChunks;

    ushort* AGh = (ushort*)d_ws;       // [PADM][128] bf16 hi plane
    ushort* AGl = AGh + PM;            // lo plane
    ushort* B0 = AGl + PM;             // [M][128] bf16 h buffer
    ushort* Wh = B0 + NM;
    ushort* Wl = Wh + 6 * 16384;
    float* st = (float*)(Wl + 6 * 16384);
    // stat slots: A-layer slots (3) then B-layer slots (2); each 256 floats
    float* stA0 = st;
    float* stA1 = st + 256;
    float* stA2 = st + 512;
    float* stB0 = st + 768;
    float* stB1 = st + 1024;
    int2* pairs = (int2*)(st + 1280);
    int* rowptr = (int*)(pairs + E);
    int* cntM = rowptr + (M + 2);
    int* bsum = cntM + nMat;
    int* srcs = bsum + 1024;

    const int* src = ei;
    const int* dst = ei + E;

    const int gemmGrid = PADM / 64;   // 1563
    const int gathGrid = (M + 7) / 8;

    // ---------------- CSR build ----------------
    k_bhist<<<nChunks, 256, 0, stream>>>(dst, cntM, E, nChunks);
    k_scanA<<<nMat / 256, 256, 0, stream>>>(cntM, bsum, nMat);
    k_scanB<<<1, 1024, 0, stream>>>(bsum, nMat / 256);
    k_scanC<<<nMat / 256, 256, 0, stream>>>(cntM, bsum);
    k_pairs<<<nChunks, 256, 0, stream>>>(src, dst, cntM, pairs, E, nChunks);
    k_csrD<<<NBKT, 256, 0, stream>>>(pairs, cntM, nChunks, rowptr, srcs, E);

    // ---------------- prep ----------------
    k_cvt<<<(int)((NM / 4 + 255) / 256), 256, 0, stream>>>(x, B0, (int)(NM / 4));
    k_wprep<<<(6 * 16384 + 255) / 256, 256, 0, stream>>>(W1, W2, Wh, Wl);
    k_zerof<<<5, 256, 0, stream>>>(st, 1280);   // all 5 stat slots

    // ---------------- layer 0 ----------------
    k_gather<<<gathGrid, 256, 0, stream>>>(B0, rowptr, srcs, nullptr, nullptr,
                                           nullptr, AGh, AGl, M);
    k_gemmA<<<gemmGrid, 256, 0, stream>>>(AGh, AGl, Wh, Wl, b1, stA0, M);
    k_gemmB<<<gemmGrid, 256, 0, stream>>>(AGh, AGl, Wh + 3 * 16384, Wl + 3 * 16384,
                                          b2, stA0, g1, be1, B0, nullptr, stB0, M);

    // ---------------- layer 1 ----------------
    k_gather<<<gathGrid, 256, 0, stream>>>(B0, rowptr, srcs, stB0, g_out, b_out,
                                           AGh, AGl, M);
    k_gemmA<<<gemmGrid, 256, 0, stream>>>(AGh, AGl, Wh + 16384, Wl + 16384,
                                          b1 + 128, stA1, M);
    k_gemmB<<<gemmGrid, 256, 0, stream>>>(AGh, AGl, Wh + 4 * 16384, Wl + 4 * 16384,
                                          b2 + 128, stA1, g1 + 128, be1 + 128,
                                          B0, nullptr, stB1, M);

    // ---------------- layer 2 ----------------
    k_gather<<<gathGrid, 256, 0, stream>>>(B0, rowptr, srcs, stB1, g_out + 128,
                                           b_out + 128, AGh, AGl, M);
    k_gemmA<<<gemmGrid, 256, 0, stream>>>(AGh, AGl, Wh + 2 * 16384, Wl + 2 * 16384,
                                          b1 + 256, stA2, M);
    k_gemmB<<<gemmGrid, 256, 0, stream>>>(AGh, AGl, Wh + 5 * 16384, Wl + 5 * 16384,
                                          b2 + 256, stA2, g1 + 256, be1 + 256,
                                          nullptr, out, nullptr, M);
}